// Round 11
// baseline (199.053 us; speedup 1.0000x reference)
//
#include <hip/hip_runtime.h>
#include <hip/hip_bf16.h>
#include <stdint.h>

typedef int v4i __attribute__((ext_vector_type(4)));

#define TOK 8192   // B*S
#define DIN 4096   // K (bytes per row, int8)
#define DOUT 4096  // N

#define NT 32      // K-tiles: 4096 / 128 bytes

// ---------------- Kernel 1: per-token dynamic quantization ----------------
__global__ __launch_bounds__(256) void quant_rows(const float* __restrict__ x,
                                                  int8_t* __restrict__ xq,
                                                  float* __restrict__ ascale) {
    const int row = blockIdx.x;
    const int t = threadIdx.x;
    const float* __restrict__ xr = x + (size_t)row * DIN;
    float4 v[4];
    float amax = 0.0f;
#pragma unroll
    for (int i = 0; i < 4; ++i) {
        v[i] = reinterpret_cast<const float4*>(xr)[t + 256 * i];
        amax = fmaxf(amax, fmaxf(fmaxf(fabsf(v[i].x), fabsf(v[i].y)),
                                 fmaxf(fabsf(v[i].z), fabsf(v[i].w))));
    }
#pragma unroll
    for (int off = 1; off < 64; off <<= 1)
        amax = fmaxf(amax, __shfl_xor(amax, off, 64));
    __shared__ float wmax[4];
    if ((t & 63) == 0) wmax[t >> 6] = amax;
    __syncthreads();
    amax = fmaxf(fmaxf(wmax[0], wmax[1]), fmaxf(wmax[2], wmax[3]));
    const float scale = fmaxf(amax, 1e-8f) / 127.0f;  // exact ref semantics
    if (t == 0) ascale[row] = scale;
    uint32_t* __restrict__ qr = reinterpret_cast<uint32_t*>(xq + (size_t)row * DIN);
#pragma unroll
    for (int i = 0; i < 4; ++i) {
        // IEEE div + rintf (half-even) == jnp.round(x / act_scale)
        int q0 = (int)fminf(fmaxf(rintf(v[i].x / scale), -128.0f), 127.0f);
        int q1 = (int)fminf(fmaxf(rintf(v[i].y / scale), -128.0f), 127.0f);
        int q2 = (int)fminf(fmaxf(rintf(v[i].z / scale), -128.0f), 127.0f);
        int q3 = (int)fminf(fmaxf(rintf(v[i].w / scale), -128.0f), 127.0f);
        qr[t + 256 * i] = (uint32_t)((q0 & 0xFF) | ((q1 & 0xFF) << 8) |
                                     ((q2 & 0xFF) << 16) | ((q3 & 0xFF) << 24));
    }
}

// ---------------- Kernel 2: weight repack int32 -> int8 ----------------
__global__ __launch_bounds__(256) void pack_w(const int* __restrict__ wq,
                                              uint32_t* __restrict__ w8) {
    const size_t i = (size_t)blockIdx.x * 256 + threadIdx.x;
    int4 a = reinterpret_cast<const int4*>(wq)[i];
    w8[i] = (uint32_t)((a.x & 0xFF) | ((a.y & 0xFF) << 8) |
                       ((a.z & 0xFF) << 16) | ((a.w & 0xFF) << 24));
}

// ---------------- Kernel 3: int8 GEMM, 256x256 tile -----------------------
// R8's verified 8-phase schedule + the R6-proven pre-barrier read pattern at
// the two tile seams: after PH4/PH8's VM(4), one extra barrier, then the
// next tile's aT/bL reads issue BEFORE the next phase's barrier (they stream
// under barrier-sync + stage-issue and drain at that phase's lgkmcnt(0)).
// Cert order VM(4) -> BAR -> reads holds at both seams (queue re-traced:
// PH4's VM(4) fully drains tile v; PH8's drains u'). All other phases are
// R8 verbatim. 10 barriers/iter. Exact int32 accumulate, fused dequant.
__global__ __launch_bounds__(512, 2) void gemm_i8(const int8_t* __restrict__ A,
                                                  const int8_t* __restrict__ B,
                                                  const float* __restrict__ ascale,
                                                  const float* __restrict__ wscale,
                                                  const float* __restrict__ bias,
                                                  float* __restrict__ C) {
    __shared__ __attribute__((aligned(16))) uint8_t lds[131072];  // A:[0,64K) B:[64K,128K)
    const int tid = threadIdx.x;
    const int bn = blockIdx.x, bm = blockIdx.y;

    // ---- staging precompute (inverse-swizzled global source, linear dest)
    const int srow = tid >> 3;  // row within 128-row half
    const int sp = tid & 7;     // 16B slot within 128B row
    const size_t soff0 = (size_t)srow * DIN + (size_t)(((sp ^ (srow & 7)) * 16));
    const size_t soff1 = soff0 + (size_t)64 * DIN;  // (srow+64)&7 == srow&7
    const uint32_t dst0 = (uint32_t)tid * 16u;
    const uint32_t dst1 = dst0 + 8192u;
    const int8_t* gA = A + (size_t)bm * 256 * DIN;
    const int8_t* gB = B + (size_t)bn * 256 * DIN;

#define STAGE_HALF(gmat, rbase, bufv, h, ktc)                                            \
    do {                                                                                 \
        const int8_t* _s = (gmat) + ((size_t)(h)*128 * DIN) + ((size_t)(ktc)*128);       \
        const uint32_t _d = (rbase) + (uint32_t)(bufv)*32768u + (uint32_t)(h)*16384u;    \
        __builtin_amdgcn_global_load_lds(                                                \
            (const __attribute__((address_space(1))) void*)(_s + soff0),                 \
            (__attribute__((address_space(3))) void*)(&lds[_d + dst0]), 16, 0, 0);       \
        __builtin_amdgcn_global_load_lds(                                                \
            (const __attribute__((address_space(1))) void*)(_s + soff1),                 \
            (__attribute__((address_space(3))) void*)(&lds[_d + dst1]), 16, 0, 0);       \
    } while (0)

    // ---- wave / lane geometry
    const int wid = tid >> 6, l = tid & 63;
    const int wm = (wid >> 2) * 128;  // 2 M-waves
    const int wn = (wid & 3) * 64;    // 4 N-waves
    const int lr = l & 15, lg = l >> 4;
    // swizzled k-slot offsets for the two K=64 sub-MFMAs of a 128B K-step
    const uint32_t koff0 = (uint32_t)(((lg) ^ (l & 7)) * 16);
    const uint32_t koff1 = (uint32_t)(((4 + lg) ^ (l & 7)) * 16);
    // per-lane ds_read base registers (koff folded in; buf1 = +32768)
    const uint32_t aRd = (uint32_t)((wm >> 7) * 16384 + lr * 128);
    const uint32_t bRd = 65536u + (uint32_t)((wn >> 7) * 16384 + ((wn & 64) + lr) * 128);
    const uint32_t a0_0 = aRd + koff0, a1_0 = aRd + koff1;
    const uint32_t a0_1 = a0_0 + 32768u, a1_1 = a1_0 + 32768u;
    const uint32_t b0_0 = bRd + koff0, b1_0 = bRd + koff1;
    const uint32_t b0_1 = b0_0 + 32768u, b1_1 = b1_0 + 32768u;

    v4i acc[8][4];
#pragma unroll
    for (int i = 0; i < 8; ++i)
#pragma unroll
        for (int j = 0; j < 4; ++j) acc[i][j] = (v4i){0, 0, 0, 0};

    v4i aT[4][2], aB[4][2], bL[2][2], bR[2][2];

#define DSR(d, b, o) asm volatile("ds_read_b128 %0, %1 offset:" o : "=v"(d) : "v"(b))

#define RD_AT(A0, A1)                                          \
    do {                                                       \
        DSR(aT[0][0], A0, "0");     DSR(aT[0][1], A1, "0");    \
        DSR(aT[1][0], A0, "2048");  DSR(aT[1][1], A1, "2048"); \
        DSR(aT[2][0], A0, "4096");  DSR(aT[2][1], A1, "4096"); \
        DSR(aT[3][0], A0, "6144");  DSR(aT[3][1], A1, "6144"); \
    } while (0)
#define RD_AB(A0, A1)                                            \
    do {                                                         \
        DSR(aB[0][0], A0, "8192");  DSR(aB[0][1], A1, "8192");   \
        DSR(aB[1][0], A0, "10240"); DSR(aB[1][1], A1, "10240");  \
        DSR(aB[2][0], A0, "12288"); DSR(aB[2][1], A1, "12288");  \
        DSR(aB[3][0], A0, "14336"); DSR(aB[3][1], A1, "14336");  \
    } while (0)
#define RD_BL(B0, B1)                                          \
    do {                                                       \
        DSR(bL[0][0], B0, "0");    DSR(bL[0][1], B1, "0");     \
        DSR(bL[1][0], B0, "2048"); DSR(bL[1][1], B1, "2048");  \
    } while (0)
#define RD_BR(B0, B1)                                          \
    do {                                                       \
        DSR(bR[0][0], B0, "4096"); DSR(bR[0][1], B1, "4096");  \
        DSR(bR[1][0], B0, "6144"); DSR(bR[1][1], B1, "6144");  \
    } while (0)

#define BAR() asm volatile("s_barrier" ::: "memory")
#define LGKM0()                                                \
    do {                                                       \
        asm volatile("s_waitcnt lgkmcnt(0)" ::: "memory");     \
        __builtin_amdgcn_sched_barrier(0);                     \
    } while (0)
#define PRIO1() __builtin_amdgcn_s_setprio(1)
#define PRIO0()                                \
    do {                                       \
        __builtin_amdgcn_sched_barrier(0);     \
        __builtin_amdgcn_s_setprio(0);         \
    } while (0)
#define VM(n) asm volatile("s_waitcnt vmcnt(" #n ")" ::: "memory")

    // kk-outer: 8 independent MFMAs, then their 8 partners (dep distance 8)
#define MFMA_K(AF, BF, MB, NB)                                                           \
    do {                                                                                 \
        _Pragma("unroll") for (int kk = 0; kk < 2; ++kk)                                 \
        _Pragma("unroll") for (int mi = 0; mi < 4; ++mi)                                 \
        _Pragma("unroll") for (int ni = 0; ni < 2; ++ni) {                               \
            acc[(MB) + mi][(NB) + ni] = __builtin_amdgcn_mfma_i32_16x16x64_i8(           \
                AF[mi][kk], BF[ni][kk], acc[(MB) + mi][(NB) + ni], 0, 0, 0);             \
        }                                                                                \
    } while (0)

    // ---- prologue: stage kt0 (all 4 halves) + kt1 (A halves); cert kt0;
    // then (seam pattern) BAR + pre-read kt0's aT/bL before the loop's BAR.
    // Loop invariant entering PH1: vm queue = [v.A(4)].
    STAGE_HALF(gA, 0u, 0, 0, 0);
    STAGE_HALF(gA, 0u, 0, 1, 0);
    STAGE_HALF(gB, 65536u, 0, 0, 0);
    STAGE_HALF(gB, 65536u, 0, 1, 0);
    STAGE_HALF(gA, 0u, 1, 0, 1);
    STAGE_HALF(gA, 0u, 1, 1, 1);
    VM(4);  // kt0's 8 loads drained; kt1.A (4) in flight
    BAR();
    RD_AT(a0_0, a1_0);
    RD_BL(b0_0, b1_0);

    // ---- main loop: u=2t (buf0, PH1-4), v=2t+1 (buf1, PH5-8)
    for (int t = 0; t < NT / 2; ++t) {
        const int cv = 2 * t + 1;
        const int cu2 = (2 * t + 2 < NT) ? 2 * t + 2 : NT - 1;  // clamp: dead stage
        const int cv2 = (2 * t + 3 < NT) ? 2 * t + 3 : NT - 1;

        // PH1: u.Q1 (aT*bL) | stage v.B0 -> buf1 | LGKM0 drains pre-reads |
        //      window: read u.aB,bR (drain at PH2's LGKM0)
        BAR();
        STAGE_HALF(gB, 65536u, 1, 0, cv);
        LGKM0();
        PRIO1();
        RD_AB(a0_0, a1_0); RD_BR(b0_0, b1_0);
        MFMA_K(aT, bL, 0, 0);
        PRIO0();

        // PH2: u.Q2 (aT*bR) | stage v.B1 -> buf1 | LGKM0 drains window reads
        BAR();
        STAGE_HALF(gB, 65536u, 1, 1, cv);
        LGKM0();
        PRIO1(); MFMA_K(aT, bR, 0, 2); PRIO0();

        // PH3: u.Q3 (aB*bL) | stage u'.A0 -> buf0 (aB reads drained PH2)
        BAR();
        STAGE_HALF(gA, 0u, 0, 0, cu2);
        LGKM0();
        PRIO1(); MFMA_K(aB, bL, 4, 0); PRIO0();

        // PH4: u.Q4 (aB*bR) | stage u'.A1 -> buf0 | VM(4): v fully landed |
        //      seam: BAR + pre-read v.aT,bL (VM -> BAR -> read)
        BAR();
        STAGE_HALF(gA, 0u, 0, 1, cu2);
        LGKM0();
        PRIO1(); MFMA_K(aB, bR, 4, 2); PRIO0();
        VM(4);
        BAR();
        RD_AT(a0_1, a1_1);
        RD_BL(b0_1, b1_1);

        // PH5: v.Q1 | stage u'.B0 -> buf0 | LGKM0 drains pre-reads | window: v.aB,bR
        BAR();
        STAGE_HALF(gB, 65536u, 0, 0, cu2);
        LGKM0();
        PRIO1();
        RD_AB(a0_1, a1_1); RD_BR(b0_1, b1_1);
        MFMA_K(aT, bL, 0, 0);
        PRIO0();

        // PH6: v.Q2 | stage u'.B1 -> buf0
        BAR();
        STAGE_HALF(gB, 65536u, 0, 1, cu2);
        LGKM0();
        PRIO1(); MFMA_K(aT, bR, 0, 2); PRIO0();

        // PH7: v.Q3 | stage v'.A0 -> buf1 (buf1.A reads drained PH6)
        BAR();
        STAGE_HALF(gA, 0u, 1, 0, cv2);
        LGKM0();
        PRIO1(); MFMA_K(aB, bL, 4, 0); PRIO0();

        // PH8: v.Q4 | stage v'.A1 -> buf1 | VM(4): u' fully landed |
        //      seam: BAR + pre-read u'.aT,bL
        BAR();
        STAGE_HALF(gA, 0u, 1, 1, cv2);
        LGKM0();
        PRIO1(); MFMA_K(aB, bR, 4, 2); PRIO0();
        VM(4);
        BAR();
        RD_AT(a0_0, a1_0);
        RD_BL(b0_0, b1_0);
    }

    // drain trailing (dead) pre-reads and clamped prefetches
    asm volatile("s_waitcnt lgkmcnt(0)" ::: "memory");
    VM(0);

    // ---- epilogue: C/D layout col=lane&15, row=(lane>>4)*4+reg
    const int col0 = bn * 256 + wn + lr;
    float wsv[4], bbv[4];
#pragma unroll
    for (int ni = 0; ni < 4; ++ni) {
        wsv[ni] = wscale[col0 + ni * 16];
        bbv[ni] = bias[col0 + ni * 16];
    }
    const int rbase = bm * 256 + wm + lg * 4;
#pragma unroll
    for (int mi = 0; mi < 8; ++mi) {
#pragma unroll
        for (int r = 0; r < 4; ++r) {
            const int row = rbase + mi * 16 + r;
            const float as = ascale[row];
            float* __restrict__ crow = C + (size_t)row * DOUT;
#pragma unroll
            for (int ni = 0; ni < 4; ++ni) {
                crow[col0 + ni * 16] = (float)acc[mi][ni][r] * as * wsv[ni] + bbv[ni];
            }
        }
    }
#undef STAGE_HALF
#undef DSR
#undef RD_AT
#undef RD_AB
#undef RD_BL
#undef RD_BR
#undef BAR
#undef LGKM0
#undef PRIO1
#undef PRIO0
#undef VM
#undef MFMA_K
}

extern "C" void kernel_launch(void* const* d_in, const int* in_sizes, int n_in,
                              void* d_out, int out_size, void* d_ws, size_t ws_size,
                              hipStream_t stream) {
    const float* x = (const float*)d_in[0];
    const int* wq = (const int*)d_in[1];
    const float* wscale = (const float*)d_in[2];
    const float* bias = (const float*)d_in[3];
    float* out = (float*)d_out;

    // workspace: xq[TOK*DIN] i8 | w8[DOUT*DIN] i8 | ascale[TOK] f32
    int8_t* xq = (int8_t*)d_ws;
    int8_t* w8 = xq + (size_t)TOK * DIN;
    float* ascale = (float*)(w8 + (size_t)DOUT * DIN);

    quant_rows<<<TOK, 256, 0, stream>>>(x, xq, ascale);
    pack_w<<<(int)(((size_t)DOUT * DIN / 4) / 256), 256, 0, stream>>>(wq, (uint32_t*)w8);
    gemm_i8<<<dim3(DOUT / 256, TOK / 256), 512, 0, stream>>>(xq, w8, ascale, wscale, bias, out);
}

// Round 12
// 191.444 us; speedup vs baseline: 1.0397x; 1.0397x over previous
//
#include <hip/hip_runtime.h>
#include <hip/hip_bf16.h>
#include <stdint.h>

typedef int v4i __attribute__((ext_vector_type(4)));

#define TOK 8192   // B*S
#define DIN 4096   // K (bytes per row, int8)
#define DOUT 4096  // N

#define NT 32      // K-tiles: 4096 / 128 bytes

// ---------------- Kernel 1: per-token dynamic quantization ----------------
__global__ __launch_bounds__(256) void quant_rows(const float* __restrict__ x,
                                                  int8_t* __restrict__ xq,
                                                  float* __restrict__ ascale) {
    const int row = blockIdx.x;
    const int t = threadIdx.x;
    const float* __restrict__ xr = x + (size_t)row * DIN;
    float4 v[4];
    float amax = 0.0f;
#pragma unroll
    for (int i = 0; i < 4; ++i) {
        v[i] = reinterpret_cast<const float4*>(xr)[t + 256 * i];
        amax = fmaxf(amax, fmaxf(fmaxf(fabsf(v[i].x), fabsf(v[i].y)),
                                 fmaxf(fabsf(v[i].z), fabsf(v[i].w))));
    }
#pragma unroll
    for (int off = 1; off < 64; off <<= 1)
        amax = fmaxf(amax, __shfl_xor(amax, off, 64));
    __shared__ float wmax[4];
    if ((t & 63) == 0) wmax[t >> 6] = amax;
    __syncthreads();
    amax = fmaxf(fmaxf(wmax[0], wmax[1]), fmaxf(wmax[2], wmax[3]));
    const float scale = fmaxf(amax, 1e-8f) / 127.0f;  // exact ref semantics
    if (t == 0) ascale[row] = scale;
    uint32_t* __restrict__ qr = reinterpret_cast<uint32_t*>(xq + (size_t)row * DIN);
#pragma unroll
    for (int i = 0; i < 4; ++i) {
        // IEEE div + rintf (half-even) == jnp.round(x / act_scale)
        int q0 = (int)fminf(fmaxf(rintf(v[i].x / scale), -128.0f), 127.0f);
        int q1 = (int)fminf(fmaxf(rintf(v[i].y / scale), -128.0f), 127.0f);
        int q2 = (int)fminf(fmaxf(rintf(v[i].z / scale), -128.0f), 127.0f);
        int q3 = (int)fminf(fmaxf(rintf(v[i].w / scale), -128.0f), 127.0f);
        qr[t + 256 * i] = (uint32_t)((q0 & 0xFF) | ((q1 & 0xFF) << 8) |
                                     ((q2 & 0xFF) << 16) | ((q3 & 0xFF) << 24));
    }
}

// ---------------- Kernel 2: weight repack int32 -> int8 ----------------
__global__ __launch_bounds__(256) void pack_w(const int* __restrict__ wq,
                                              uint32_t* __restrict__ w8) {
    const size_t i = (size_t)blockIdx.x * 256 + threadIdx.x;
    int4 a = reinterpret_cast<const int4*>(wq)[i];
    w8[i] = (uint32_t)((a.x & 0xFF) | ((a.y & 0xFF) << 8) |
                       ((a.z & 0xFF) << 16) | ((a.w & 0xFF) << 24));
}

// ---------------- Kernel 3: int8 GEMM, 128x128 tile, 2 blocks/CU ----------
// R8's verified 8-phase schedule, parameter-halved: 128x128 tile, 256
// threads (4 waves 2x2, each 64x64 output), 64 KiB LDS -> TWO independent
// blocks co-resident per CU. Decoupled barrier domains let one block's
// MFMAs fill the other's barrier/lgkm stalls (m97/m114 mechanism). All
// structure is R8 verbatim: stage-half order {v.B0, v.B1, u'.A0, u'.A1},
// VM(4) at PH4/PH8 (STAGE_HALF = 2 loads, identical vmcnt units), PH1/PH5
// pre-reads (aT,bL) + window reads (aB,bR), kk-outer MFMA, XOR swizzle
// (32-row staging stride: (row+32)&7 == row&7). Exact int32 accumulate.
__global__ __launch_bounds__(256, 2) void gemm_i8(const int8_t* __restrict__ A,
                                                  const int8_t* __restrict__ B,
                                                  const float* __restrict__ ascale,
                                                  const float* __restrict__ wscale,
                                                  const float* __restrict__ bias,
                                                  float* __restrict__ C) {
    __shared__ __attribute__((aligned(16))) uint8_t lds[65536];  // A:[0,32K) B:[32K,64K)
    const int tid = threadIdx.x;
    const int bn = blockIdx.x, bm = blockIdx.y;

    // ---- staging precompute (inverse-swizzled global source, linear dest)
    const int srow = tid >> 3;  // row 0..31 within a 32-row load group
    const int sp = tid & 7;     // 16B slot within 128B row
    const size_t soff0 = (size_t)srow * DIN + (size_t)(((sp ^ (srow & 7)) * 16));
    const size_t soff1 = soff0 + (size_t)32 * DIN;  // (srow+32)&7 == srow&7
    const uint32_t dst0 = (uint32_t)tid * 16u;
    const uint32_t dst1 = dst0 + 4096u;
    const int8_t* gA = A + (size_t)bm * 128 * DIN;
    const int8_t* gB = B + (size_t)bn * 128 * DIN;

    // STAGE_HALF: one 64-row half (8KB) of a 128x128B tile region = 2 loads.
#define STAGE_HALF(gmat, rbase, bufv, h, ktc)                                            \
    do {                                                                                 \
        const int8_t* _s = (gmat) + ((size_t)(h)*64 * DIN) + ((size_t)(ktc)*128);        \
        const uint32_t _d = (rbase) + (uint32_t)(bufv)*16384u + (uint32_t)(h)*8192u;     \
        __builtin_amdgcn_global_load_lds(                                                \
            (const __attribute__((address_space(1))) void*)(_s + soff0),                 \
            (__attribute__((address_space(3))) void*)(&lds[_d + dst0]), 16, 0, 0);       \
        __builtin_amdgcn_global_load_lds(                                                \
            (const __attribute__((address_space(1))) void*)(_s + soff1),                 \
            (__attribute__((address_space(3))) void*)(&lds[_d + dst1]), 16, 0, 0);       \
    } while (0)

    // ---- wave / lane geometry: 4 waves 2x2, each 64x64 output
    const int wid = tid >> 6, l = tid & 63;
    const int wm = (wid >> 1) * 64;  // 2 M-waves
    const int wn = (wid & 1) * 64;   // 2 N-waves
    const int lr = l & 15, lg = l >> 4;
    // swizzled k-slot offsets for the two K=64 sub-MFMAs of a 128B K-step
    const uint32_t koff0 = (uint32_t)(((lg) ^ (l & 7)) * 16);
    const uint32_t koff1 = (uint32_t)(((4 + lg) ^ (l & 7)) * 16);
    // per-lane ds_read base registers (koff folded in; buf1 = +16384)
    const uint32_t aRd = (uint32_t)((wm + lr) * 128);
    const uint32_t bRd = 32768u + (uint32_t)((wn + lr) * 128);
    const uint32_t a0_0 = aRd + koff0, a1_0 = aRd + koff1;
    const uint32_t a0_1 = a0_0 + 16384u, a1_1 = a1_0 + 16384u;
    const uint32_t b0_0 = bRd + koff0, b1_0 = bRd + koff1;
    const uint32_t b0_1 = b0_0 + 16384u, b1_1 = b1_0 + 16384u;

    v4i acc[4][4];
#pragma unroll
    for (int i = 0; i < 4; ++i)
#pragma unroll
        for (int j = 0; j < 4; ++j) acc[i][j] = (v4i){0, 0, 0, 0};

    v4i aT[2][2], aB[2][2], bL[2][2], bR[2][2];

#define DSR(d, b, o) asm volatile("ds_read_b128 %0, %1 offset:" o : "=v"(d) : "v"(b))

#define RD_AT(A0, A1)                                          \
    do {                                                       \
        DSR(aT[0][0], A0, "0");     DSR(aT[0][1], A1, "0");    \
        DSR(aT[1][0], A0, "2048");  DSR(aT[1][1], A1, "2048"); \
    } while (0)
#define RD_AB(A0, A1)                                          \
    do {                                                       \
        DSR(aB[0][0], A0, "4096");  DSR(aB[0][1], A1, "4096"); \
        DSR(aB[1][0], A0, "6144");  DSR(aB[1][1], A1, "6144"); \
    } while (0)
#define RD_BL(B0, B1)                                          \
    do {                                                       \
        DSR(bL[0][0], B0, "0");    DSR(bL[0][1], B1, "0");     \
        DSR(bL[1][0], B0, "2048"); DSR(bL[1][1], B1, "2048");  \
    } while (0)
#define RD_BR(B0, B1)                                          \
    do {                                                       \
        DSR(bR[0][0], B0, "4096"); DSR(bR[0][1], B1, "4096");  \
        DSR(bR[1][0], B0, "6144"); DSR(bR[1][1], B1, "6144");  \
    } while (0)

#define BAR() asm volatile("s_barrier" ::: "memory")
#define LGKM0()                                                \
    do {                                                       \
        asm volatile("s_waitcnt lgkmcnt(0)" ::: "memory");     \
        __builtin_amdgcn_sched_barrier(0);                     \
    } while (0)
#define PRIO1() __builtin_amdgcn_s_setprio(1)
#define PRIO0()                                \
    do {                                       \
        __builtin_amdgcn_sched_barrier(0);     \
        __builtin_amdgcn_s_setprio(0);         \
    } while (0)
#define VM(n) asm volatile("s_waitcnt vmcnt(" #n ")" ::: "memory")

    // kk-outer: 4 independent MFMAs, then their 4 partners (dep distance 4)
#define MFMA_K(AF, BF, MB, NB)                                                           \
    do {                                                                                 \
        _Pragma("unroll") for (int kk = 0; kk < 2; ++kk)                                 \
        _Pragma("unroll") for (int mi = 0; mi < 2; ++mi)                                 \
        _Pragma("unroll") for (int ni = 0; ni < 2; ++ni) {                               \
            acc[(MB) + mi][(NB) + ni] = __builtin_amdgcn_mfma_i32_16x16x64_i8(           \
                AF[mi][kk], BF[ni][kk], acc[(MB) + mi][(NB) + ni], 0, 0, 0);             \
        }                                                                                \
    } while (0)

    // ---- prologue: stage kt0 (all 4 halves) + kt1 (A halves); cert kt0.
    // Loop invariant entering PH1: vm queue = [v.A(4)].
    STAGE_HALF(gA, 0u, 0, 0, 0);
    STAGE_HALF(gA, 0u, 0, 1, 0);
    STAGE_HALF(gB, 32768u, 0, 0, 0);
    STAGE_HALF(gB, 32768u, 0, 1, 0);
    STAGE_HALF(gA, 0u, 1, 0, 1);
    STAGE_HALF(gA, 0u, 1, 1, 1);
    VM(4);  // kt0's 8 loads drained; kt1.A (4) in flight

    // ---- main loop: u=2t (buf0, PH1-4), v=2t+1 (buf1, PH5-8)
    for (int t = 0; t < NT / 2; ++t) {
        const int cv = 2 * t + 1;
        const int cu2 = (2 * t + 2 < NT) ? 2 * t + 2 : NT - 1;  // clamp: dead stage
        const int cv2 = (2 * t + 3 < NT) ? 2 * t + 3 : NT - 1;

        // PH1: u.Q1 (aT*bL) | stage v.B0 -> buf1 | pre-read aT,bL | window aB,bR
        BAR();
        STAGE_HALF(gB, 32768u, 1, 0, cv);
        RD_AT(a0_0, a1_0); RD_BL(b0_0, b1_0);
        LGKM0();
        PRIO1();
        RD_AB(a0_0, a1_0); RD_BR(b0_0, b1_0);
        MFMA_K(aT, bL, 0, 0);
        PRIO0();

        // PH2: u.Q2 (aT*bR) | stage v.B1 -> buf1 | LGKM0 drains window reads
        BAR();
        STAGE_HALF(gB, 32768u, 1, 1, cv);
        LGKM0();
        PRIO1(); MFMA_K(aT, bR, 0, 2); PRIO0();

        // PH3: u.Q3 (aB*bL) | stage u'.A0 -> buf0 (aB reads drained PH2)
        BAR();
        STAGE_HALF(gA, 0u, 0, 0, cu2);
        LGKM0();
        PRIO1(); MFMA_K(aB, bL, 2, 0); PRIO0();

        // PH4: u.Q4 (aB*bR) | stage u'.A1 -> buf0 | VM(4): v fully landed
        BAR();
        STAGE_HALF(gA, 0u, 0, 1, cu2);
        LGKM0();
        PRIO1(); MFMA_K(aB, bR, 2, 2); PRIO0();
        VM(4);

        // PH5: v.Q1 | stage u'.B0 -> buf0 | pre-read v.aT,bL | window v.aB,bR
        BAR();
        STAGE_HALF(gB, 32768u, 0, 0, cu2);
        RD_AT(a0_1, a1_1); RD_BL(b0_1, b1_1);
        LGKM0();
        PRIO1();
        RD_AB(a0_1, a1_1); RD_BR(b0_1, b1_1);
        MFMA_K(aT, bL, 0, 0);
        PRIO0();

        // PH6: v.Q2 | stage u'.B1 -> buf0
        BAR();
        STAGE_HALF(gB, 32768u, 0, 1, cu2);
        LGKM0();
        PRIO1(); MFMA_K(aT, bR, 0, 2); PRIO0();

        // PH7: v.Q3 | stage v'.A0 -> buf1 (buf1.A reads drained PH6)
        BAR();
        STAGE_HALF(gA, 0u, 1, 0, cv2);
        LGKM0();
        PRIO1(); MFMA_K(aB, bL, 2, 0); PRIO0();

        // PH8: v.Q4 | stage v'.A1 -> buf1 | VM(4): u' fully landed
        BAR();
        STAGE_HALF(gA, 0u, 1, 1, cv2);
        LGKM0();
        PRIO1(); MFMA_K(aB, bR, 2, 2); PRIO0();
        VM(4);
    }

    // drain trailing reads and clamped prefetches
    asm volatile("s_waitcnt lgkmcnt(0)" ::: "memory");
    VM(0);

    // ---- epilogue: C/D layout col=lane&15, row=(lane>>4)*4+reg
    const int col0 = bn * 128 + wn + lr;
    float wsv[4], bbv[4];
#pragma unroll
    for (int ni = 0; ni < 4; ++ni) {
        wsv[ni] = wscale[col0 + ni * 16];
        bbv[ni] = bias[col0 + ni * 16];
    }
    const int rbase = bm * 128 + wm + lg * 4;
#pragma unroll
    for (int mi = 0; mi < 4; ++mi) {
#pragma unroll
        for (int r = 0; r < 4; ++r) {
            const int row = rbase + mi * 16 + r;
            const float as = ascale[row];
            float* __restrict__ crow = C + (size_t)row * DOUT;
#pragma unroll
            for (int ni = 0; ni < 4; ++ni) {
                crow[col0 + ni * 16] = (float)acc[mi][ni][r] * as * wsv[ni] + bbv[ni];
            }
        }
    }
#undef STAGE_HALF
#undef DSR
#undef RD_AT
#undef RD_AB
#undef RD_BL
#undef RD_BR
#undef BAR
#undef LGKM0
#undef PRIO1
#undef PRIO0
#undef VM
#undef MFMA_K
}

extern "C" void kernel_launch(void* const* d_in, const int* in_sizes, int n_in,
                              void* d_out, int out_size, void* d_ws, size_t ws_size,
                              hipStream_t stream) {
    const float* x = (const float*)d_in[0];
    const int* wq = (const int*)d_in[1];
    const float* wscale = (const float*)d_in[2];
    const float* bias = (const float*)d_in[3];
    float* out = (float*)d_out;

    // workspace: xq[TOK*DIN] i8 | w8[DOUT*DIN] i8 | ascale[TOK] f32
    int8_t* xq = (int8_t*)d_ws;
    int8_t* w8 = xq + (size_t)TOK * DIN;
    float* ascale = (float*)(w8 + (size_t)DOUT * DIN);

    quant_rows<<<TOK, 256, 0, stream>>>(x, xq, ascale);
    pack_w<<<(int)(((size_t)DOUT * DIN / 4) / 256), 256, 0, stream>>>(wq, (uint32_t*)w8);
    gemm_i8<<<dim3(DOUT / 128, TOK / 128), 256, 0, stream>>>(xq, w8, ascale, wscale, bias, out);
}